// Round 1
// baseline (3908.207 us; speedup 1.0000x reference)
//
#include <hip/hip_runtime.h>

// GNN: 8 graph layers (message -> segment_sum -> update) with skip-weighted combos.
// Factorization: m_e = ReLU(p[src] + Wme^T ea_e), p = Wmh^T h + bm  (bias folded in p).

#define WAVE 64

// ---------------- generic node linear ----------------
// out[n][f] = act( bias[f] + sum_{k<K1} A[n][k] W[k][f] + sum_{k<K2} B[n][k] W[K1+k][f] )
// optionally followed by skip combine: out = sw[base+nprev]*act + sum_j sw[base+j]*q_j[n][f]
template<int K1, int K2, bool RELU, bool SKIP>
__global__ __launch_bounds__(256) void lin_kernel(
    const float* __restrict__ A, const float* __restrict__ B,
    const float* __restrict__ W, const float* __restrict__ bias,
    float* __restrict__ out, int N,
    const float* __restrict__ q0, const float* __restrict__ q1,
    const float* __restrict__ q2, const float* __restrict__ q3,
    const float* __restrict__ q4, const float* __restrict__ q5,
    const float* __restrict__ sw, int swbase, int nprev)
{
    constexpr int K = K1 + K2;
    __shared__ float Wl[K * 64];
    __shared__ float bl[64];
    for (int i = threadIdx.x; i < K * 64; i += blockDim.x) Wl[i] = W[i];
    if (threadIdx.x < 64) bl[threadIdx.x] = bias[threadIdx.x];
    __syncthreads();

    // hoist skip weights (uniform scalar loads)
    float swself = 1.0f, s0 = 0, s1 = 0, s2 = 0, s3 = 0, s4 = 0, s5 = 0;
    if (SKIP) {
        swself = sw[swbase + nprev];
        if (nprev > 0) s0 = sw[swbase + 0];
        if (nprev > 1) s1 = sw[swbase + 1];
        if (nprev > 2) s2 = sw[swbase + 2];
        if (nprev > 3) s3 = sw[swbase + 3];
        if (nprev > 4) s4 = sw[swbase + 4];
        if (nprev > 5) s5 = sw[swbase + 5];
    }

    int lane = threadIdx.x & 63;
    int gwave = blockIdx.x * (blockDim.x >> 6) + (threadIdx.x >> 6);
    int nw = gridDim.x * (blockDim.x >> 6);

    for (int n = gwave; n < N; n += nw) {
        float acc = bl[lane];
        const float* ar = A + (size_t)n * K1;
#pragma unroll
        for (int kk = 0; kk < K1 / 4; ++kk) {
            float4 a4 = *reinterpret_cast<const float4*>(ar + 4 * kk);
            acc = fmaf(a4.x, Wl[(4 * kk + 0) * 64 + lane], acc);
            acc = fmaf(a4.y, Wl[(4 * kk + 1) * 64 + lane], acc);
            acc = fmaf(a4.z, Wl[(4 * kk + 2) * 64 + lane], acc);
            acc = fmaf(a4.w, Wl[(4 * kk + 3) * 64 + lane], acc);
        }
        if (K2 > 0) {
            const float* br = B + (size_t)n * K2;
#pragma unroll
            for (int kk = 0; kk < K2 / 4; ++kk) {
                float4 a4 = *reinterpret_cast<const float4*>(br + 4 * kk);
                acc = fmaf(a4.x, Wl[(K1 + 4 * kk + 0) * 64 + lane], acc);
                acc = fmaf(a4.y, Wl[(K1 + 4 * kk + 1) * 64 + lane], acc);
                acc = fmaf(a4.z, Wl[(K1 + 4 * kk + 2) * 64 + lane], acc);
                acc = fmaf(a4.w, Wl[(K1 + 4 * kk + 3) * 64 + lane], acc);
            }
        }
        if (RELU) acc = fmaxf(acc, 0.0f);
        if (SKIP) {
            size_t off = (size_t)n * 64 + lane;
            float r = swself * acc;
            if (nprev > 0) r = fmaf(s0, q0[off], r);
            if (nprev > 1) r = fmaf(s1, q1[off], r);
            if (nprev > 2) r = fmaf(s2, q2[off], r);
            if (nprev > 3) r = fmaf(s3, q3[off], r);
            if (nprev > 4) r = fmaf(s4, q4[off], r);
            if (nprev > 5) r = fmaf(s5, q5[off], r);
            acc = r;
        }
        out[(size_t)n * 64 + lane] = acc;
    }
}

// ---------------- edge message + aggregate (HID outputs) ----------------
// agg[dst][f] += ReLU(p[src][f] + sum_j ea[e][j]*Wme[j][f])
__global__ __launch_bounds__(256) void edge_kernel(
    const int* __restrict__ ei, const float* __restrict__ ea,
    const float* __restrict__ p, const float* __restrict__ Wme,
    float* __restrict__ agg, int E)
{
    int lane = threadIdx.x & 63;
    int gwave = blockIdx.x * (blockDim.x >> 6) + (threadIdx.x >> 6);
    int nw = gridDim.x * (blockDim.x >> 6);
    float w0 = Wme[0 * 64 + lane];
    float w1 = Wme[1 * 64 + lane];
    float w2 = Wme[2 * 64 + lane];
    float w3 = Wme[3 * 64 + lane];
    for (int e = gwave; e < E; e += nw) {
        int s = ei[e];
        int d = ei[E + e];
        float4 a = *reinterpret_cast<const float4*>(ea + (size_t)4 * e);
        float v = p[(size_t)s * 64 + lane];
        v = fmaf(a.x, w0, v);
        v = fmaf(a.y, w1, v);
        v = fmaf(a.z, w2, v);
        v = fmaf(a.w, w3, v);
        v = fmaxf(v, 0.0f);
        atomicAdd(agg + (size_t)d * 64 + lane, v);
    }
}

// ---------------- last layer (OUT=4) variants ----------------
__global__ __launch_bounds__(256) void pl_kernel(
    const float* __restrict__ A, const float* __restrict__ W,
    const float* __restrict__ bias, float* __restrict__ out, int N)
{
    __shared__ float Wl[64 * 4];
    __shared__ float bl[4];
    for (int i = threadIdx.x; i < 256; i += blockDim.x) Wl[i] = W[i];
    if (threadIdx.x < 4) bl[threadIdx.x] = bias[threadIdx.x];
    __syncthreads();
    int t = blockIdx.x * blockDim.x + threadIdx.x;
    int nt = gridDim.x * blockDim.x;
    for (int idx = t; idx < N * 4; idx += nt) {
        int n = idx >> 2, f = idx & 3;
        float acc = bl[f];
        const float* ar = A + (size_t)n * 64;
#pragma unroll
        for (int kk = 0; kk < 16; ++kk) {
            float4 a4 = *reinterpret_cast<const float4*>(ar + 4 * kk);
            acc = fmaf(a4.x, Wl[(4 * kk + 0) * 4 + f], acc);
            acc = fmaf(a4.y, Wl[(4 * kk + 1) * 4 + f], acc);
            acc = fmaf(a4.z, Wl[(4 * kk + 2) * 4 + f], acc);
            acc = fmaf(a4.w, Wl[(4 * kk + 3) * 4 + f], acc);
        }
        out[idx] = acc;
    }
}

__global__ __launch_bounds__(256) void edge4_kernel(
    const int* __restrict__ ei, const float* __restrict__ ea,
    const float* __restrict__ p4, const float* __restrict__ Wme,
    float* __restrict__ agg4, int E)
{
    int lane = threadIdx.x & 63;
    int f = lane & 3;
    int gwave = blockIdx.x * (blockDim.x >> 6) + (threadIdx.x >> 6);
    int nw = gridDim.x * (blockDim.x >> 6);
    float w0 = Wme[0 * 4 + f];
    float w1 = Wme[1 * 4 + f];
    float w2 = Wme[2 * 4 + f];
    float w3 = Wme[3 * 4 + f];
    for (int e0 = gwave * 16; e0 < E; e0 += nw * 16) {
        int e = e0 + (lane >> 2);
        if (e < E) {
            int s = ei[e];
            int d = ei[E + e];
            float4 a = *reinterpret_cast<const float4*>(ea + (size_t)4 * e);
            float v = p4[(size_t)s * 4 + f];
            v = fmaf(a.x, w0, v);
            v = fmaf(a.y, w1, v);
            v = fmaf(a.z, w2, v);
            v = fmaf(a.w, w3, v);
            v = fmaxf(v, 0.0f);
            atomicAdd(agg4 + (size_t)d * 4 + f, v);
        }
    }
}

__global__ __launch_bounds__(256) void ul_kernel(
    const float* __restrict__ A, const float* __restrict__ agg4,
    const float* __restrict__ W /*[68][4]*/, const float* __restrict__ bias,
    float* __restrict__ out, int N)
{
    __shared__ float Wl[68 * 4];
    __shared__ float bl[4];
    for (int i = threadIdx.x; i < 68 * 4; i += blockDim.x) Wl[i] = W[i];
    if (threadIdx.x < 4) bl[threadIdx.x] = bias[threadIdx.x];
    __syncthreads();
    int t = blockIdx.x * blockDim.x + threadIdx.x;
    int nt = gridDim.x * blockDim.x;
    for (int idx = t; idx < N * 4; idx += nt) {
        int n = idx >> 2, f = idx & 3;
        float acc = bl[f];
        const float* ar = A + (size_t)n * 64;
#pragma unroll
        for (int kk = 0; kk < 16; ++kk) {
            float4 a4 = *reinterpret_cast<const float4*>(ar + 4 * kk);
            acc = fmaf(a4.x, Wl[(4 * kk + 0) * 4 + f], acc);
            acc = fmaf(a4.y, Wl[(4 * kk + 1) * 4 + f], acc);
            acc = fmaf(a4.z, Wl[(4 * kk + 2) * 4 + f], acc);
            acc = fmaf(a4.w, Wl[(4 * kk + 3) * 4 + f], acc);
        }
        float4 g = *reinterpret_cast<const float4*>(agg4 + (size_t)n * 4);
        acc = fmaf(g.x, Wl[(64 + 0) * 4 + f], acc);
        acc = fmaf(g.y, Wl[(64 + 1) * 4 + f], acc);
        acc = fmaf(g.z, Wl[(64 + 2) * 4 + f], acc);
        acc = fmaf(g.w, Wl[(64 + 3) * 4 + f], acc);
        out[idx] = fmaxf(acc, 0.0f);
    }
}

extern "C" void kernel_launch(void* const* d_in, const int* in_sizes, int n_in,
                              void* d_out, int out_size, void* d_ws, size_t ws_size,
                              hipStream_t stream)
{
    const float* x      = (const float*)d_in[0];
    const int*   ei     = (const int*)d_in[1];
    const float* ea     = (const float*)d_in[2];
    const float* Wm1    = (const float*)d_in[3];   // [12][64]
    const float* bm1    = (const float*)d_in[4];
    const float* Wu1    = (const float*)d_in[5];   // [72][64]
    const float* bu1    = (const float*)d_in[6];
    const float* Wm_mid = (const float*)d_in[7];   // [5][68][64]
    const float* bm_mid = (const float*)d_in[8];   // [5][64]
    const float* Wu_mid = (const float*)d_in[9];   // [5][128][64]
    const float* bu_mid = (const float*)d_in[10];  // [5][64]
    const float* WmL    = (const float*)d_in[11];  // [68][4]
    const float* bmL    = (const float*)d_in[12];
    const float* WuL    = (const float*)d_in[13];  // [68][4]
    const float* buL    = (const float*)d_in[14];
    const float* sw     = (const float*)d_in[15];  // [27]

    const int N = in_sizes[0] / 8;
    const int E = in_sizes[2] / 4;

    float* ws = (float*)d_ws;
    size_t nh = (size_t)N * 64;
    float* p    = ws;
    float* agg  = ws + nh;
    float* x1   = ws + 2 * nh;
    float* x2w  = ws + 3 * nh;
    float* x3w  = ws + 4 * nh;
    float* x4w  = ws + 5 * nh;
    float* x5w  = ws + 6 * nh;
    float* x6w  = ws + 7 * nh;
    float* x7w  = p;                  // p free after last mid edge pass
    float* p4   = agg;                // [N*4], agg free after last mid update
    float* agg4 = agg + (size_t)N * 4;

    dim3 blk(256);
    dim3 gLin(2048), gEdge(2048), g4(1024);
    const float* nul = nullptr;

    // ---- layer 1 ----
    lin_kernel<8, 0, false, false><<<gLin, blk, 0, stream>>>(
        x, nul, Wm1, bm1, p, N, nul, nul, nul, nul, nul, nul, sw, 0, 0);
    hipMemsetAsync(agg, 0, nh * sizeof(float), stream);
    edge_kernel<<<gEdge, blk, 0, stream>>>(ei, ea, p, Wm1 + 8 * 64, agg, E);
    lin_kernel<8, 64, true, false><<<gLin, blk, 0, stream>>>(
        x, agg, Wu1, bu1, x1, N, nul, nul, nul, nul, nul, nul, sw, 0, 0);

    // ---- mid layers ----
    struct MidStep {
        int mi; const float* in; float* out; int swbase; int nprev;
        const float *q0, *q1, *q2, *q3, *q4, *q5;
    };
    MidStep steps[6] = {
        {0, x1,  x2w, 0,  1, x1,  nul, nul, nul, nul, nul},
        {1, x2w, x3w, 2,  2, x1,  x2w, nul, nul, nul, nul},
        {2, x3w, x4w, 5,  3, x1,  x2w, x3w, nul, nul, nul},
        {2, x4w, x5w, 9,  4, x1,  x2w, x3w, x4w, nul, nul},  // reuses mid layer 2 (faithful to bug)
        {3, x5w, x6w, 14, 5, x1,  x2w, x3w, x4w, x5w, nul},
        {4, x6w, x7w, 20, 6, x1,  x2w, x3w, x4w, x5w, x6w},
    };
    for (int li = 0; li < 6; ++li) {
        const MidStep& st = steps[li];
        const float* Wm = Wm_mid + (size_t)st.mi * 68 * 64;
        const float* bm = bm_mid + (size_t)st.mi * 64;
        const float* Wu = Wu_mid + (size_t)st.mi * 128 * 64;
        const float* bu = bu_mid + (size_t)st.mi * 64;
        lin_kernel<64, 0, false, false><<<gLin, blk, 0, stream>>>(
            st.in, nul, Wm, bm, p, N, nul, nul, nul, nul, nul, nul, sw, 0, 0);
        hipMemsetAsync(agg, 0, nh * sizeof(float), stream);
        edge_kernel<<<gEdge, blk, 0, stream>>>(ei, ea, p, Wm + 64 * 64, agg, E);
        lin_kernel<64, 64, true, true><<<gLin, blk, 0, stream>>>(
            st.in, agg, Wu, bu, st.out, N,
            st.q0, st.q1, st.q2, st.q3, st.q4, st.q5, sw, st.swbase, st.nprev);
    }

    // ---- last layer (OUT=4) ----
    pl_kernel<<<g4, blk, 0, stream>>>(x7w, WmL, bmL, p4, N);
    hipMemsetAsync(agg4, 0, (size_t)N * 4 * sizeof(float), stream);
    edge4_kernel<<<gEdge, blk, 0, stream>>>(ei, ea, p4, WmL + 64 * 4, agg4, E);
    ul_kernel<<<g4, blk, 0, stream>>>(x7w, agg4, WuL, buL, (float*)d_out, N);
}

// Round 2
// 3240.697 us; speedup vs baseline: 1.2060x; 1.2060x over previous
//
#include <hip/hip_runtime.h>

// GNN: 8 graph layers (message -> segment_sum -> update) + skip combos.
// m_e = ReLU(p[src] + ea_e @ Wme), p = h @ Wmh + bm (bias folded into p).
// Aggregation via CSR-by-dst (built once per launch) -> register accumulate,
// no atomics. Node linears: W transposed in LDS (odd float4 stride -> no bank
// conflicts on ds_read_b128), M=4 nodes per wave to amortize W reads.

#define WAVE 64

// ---------------- CSR build ----------------
__global__ __launch_bounds__(256) void hist_kernel(
    const int* __restrict__ ei, int* __restrict__ cnt, int E)
{
    int t = blockIdx.x * blockDim.x + threadIdx.x;
    int nt = gridDim.x * blockDim.x;
    for (int e = t; e < E; e += nt) atomicAdd(&cnt[ei[E + e]], 1);
}

// per-block scan of 1024 counts (256 thr x 4), exclusive-within-block
__global__ __launch_bounds__(256) void scan1_kernel(
    const int* __restrict__ cnt, int* __restrict__ out, int* __restrict__ bsum, int N)
{
    __shared__ int lds[256];
    int t = threadIdx.x;
    int base = blockIdx.x * 1024 + t * 4;
    int v0 = (base + 0 < N) ? cnt[base + 0] : 0;
    int v1 = (base + 1 < N) ? cnt[base + 1] : 0;
    int v2 = (base + 2 < N) ? cnt[base + 2] : 0;
    int v3 = (base + 3 < N) ? cnt[base + 3] : 0;
    int tsum = v0 + v1 + v2 + v3;
    lds[t] = tsum;
    __syncthreads();
    for (int off = 1; off < 256; off <<= 1) {
        int x = 0;
        if (t >= off) x = lds[t - off];
        __syncthreads();
        if (t >= off) lds[t] += x;
        __syncthreads();
    }
    int run = lds[t] - tsum;  // exclusive
    if (base + 0 < N) out[base + 0] = run; run += v0;
    if (base + 1 < N) out[base + 1] = run; run += v1;
    if (base + 2 < N) out[base + 2] = run; run += v2;
    if (base + 3 < N) out[base + 3] = run;
    if (t == 255) bsum[blockIdx.x] = lds[255];
}

// single-block exclusive scan of block sums (any B)
__global__ __launch_bounds__(256) void scan2_kernel(int* __restrict__ bsum, int B)
{
    __shared__ int lds[256];
    __shared__ int carry;
    int t = threadIdx.x;
    if (t == 0) carry = 0;
    __syncthreads();
    for (int start = 0; start < B; start += 256) {
        int i = start + t;
        int v = (i < B) ? bsum[i] : 0;
        lds[t] = v;
        __syncthreads();
        for (int off = 1; off < 256; off <<= 1) {
            int x = 0;
            if (t >= off) x = lds[t - off];
            __syncthreads();
            if (t >= off) lds[t] += x;
            __syncthreads();
        }
        if (i < B) bsum[i] = carry + lds[t] - v;  // exclusive
        __syncthreads();
        if (t == 255) carry += lds[255];
        __syncthreads();
    }
}

__global__ __launch_bounds__(256) void scan3_kernel(
    int* __restrict__ rowptr, int* __restrict__ cursor,
    const int* __restrict__ bsum, int N, int E)
{
    int t = blockIdx.x * blockDim.x + threadIdx.x;
    int nt = gridDim.x * blockDim.x;
    for (int i = t; i < N; i += nt) {
        int v = rowptr[i] + bsum[i >> 10];
        rowptr[i] = v;
        cursor[i] = v;
    }
    if (t == 0) rowptr[N] = E;
}

__global__ __launch_bounds__(256) void scatter_kernel(
    const int* __restrict__ ei, const float* __restrict__ ea,
    int* __restrict__ cursor, int* __restrict__ srcp, float* __restrict__ eap, int E)
{
    int t = blockIdx.x * blockDim.x + threadIdx.x;
    int nt = gridDim.x * blockDim.x;
    for (int e = t; e < E; e += nt) {
        int d = ei[E + e];
        int pos = atomicAdd(&cursor[d], 1);
        srcp[pos] = ei[e];
        *reinterpret_cast<float4*>(eap + (size_t)4 * pos) =
            *reinterpret_cast<const float4*>(ea + (size_t)4 * e);
    }
}

// ---------------- node linear (transposed W in LDS, M=4 nodes/wave) ----------------
template<int K1, int K2, bool RELU, bool SKIP>
__global__ __launch_bounds__(256) void lin_kernel(
    const float* __restrict__ A, const float* __restrict__ B,
    const float* __restrict__ W, const float* __restrict__ bias,
    float* __restrict__ out, int N,
    const float* __restrict__ q0, const float* __restrict__ q1,
    const float* __restrict__ q2, const float* __restrict__ q3,
    const float* __restrict__ q4, const float* __restrict__ q5,
    const float* __restrict__ sw, int swbase, int nprev)
{
    constexpr int K = K1 + K2;
    constexpr int NC = K / 4;                  // float4 chunks along K
    constexpr int S = NC + ((NC & 1) ^ 1);     // odd stride -> b128 bank-quad spread
    constexpr int M = 4;
    __shared__ float4 Wl[64 * S];
    // load + transpose: Wl[f][c] = W[4c..4c+3][f]
    for (int idx = threadIdx.x; idx < 64 * NC; idx += blockDim.x) {
        int f = idx & 63, c = idx >> 6;
        float4 w;
        w.x = W[(4 * c + 0) * 64 + f];
        w.y = W[(4 * c + 1) * 64 + f];
        w.z = W[(4 * c + 2) * 64 + f];
        w.w = W[(4 * c + 3) * 64 + f];
        Wl[f * S + c] = w;
    }
    __syncthreads();

    int lane = threadIdx.x & 63;
    float bv = bias[lane];
    float swself = 1.0f, s0 = 0, s1 = 0, s2 = 0, s3 = 0, s4 = 0, s5 = 0;
    if (SKIP) {
        swself = sw[swbase + nprev];
        if (nprev > 0) s0 = sw[swbase + 0];
        if (nprev > 1) s1 = sw[swbase + 1];
        if (nprev > 2) s2 = sw[swbase + 2];
        if (nprev > 3) s3 = sw[swbase + 3];
        if (nprev > 4) s4 = sw[swbase + 4];
        if (nprev > 5) s5 = sw[swbase + 5];
    }

    int gwave = blockIdx.x * (blockDim.x >> 6) + (threadIdx.x >> 6);
    int nw = gridDim.x * (blockDim.x >> 6);
    const float4* w4 = &Wl[lane * S];

    for (int base = gwave * M; base < N; base += nw * M) {
        int n0 = base, n1 = min(base + 1, N - 1), n2 = min(base + 2, N - 1), n3 = min(base + 3, N - 1);
        float acc0 = bv, acc1 = bv, acc2 = bv, acc3 = bv;
#pragma unroll
        for (int c = 0; c < K1 / 4; ++c) {
            float4 w = w4[c];
            float4 a0 = *reinterpret_cast<const float4*>(A + (size_t)n0 * K1 + 4 * c);
            float4 a1 = *reinterpret_cast<const float4*>(A + (size_t)n1 * K1 + 4 * c);
            float4 a2 = *reinterpret_cast<const float4*>(A + (size_t)n2 * K1 + 4 * c);
            float4 a3 = *reinterpret_cast<const float4*>(A + (size_t)n3 * K1 + 4 * c);
            acc0 = fmaf(a0.x, w.x, fmaf(a0.y, w.y, fmaf(a0.z, w.z, fmaf(a0.w, w.w, acc0))));
            acc1 = fmaf(a1.x, w.x, fmaf(a1.y, w.y, fmaf(a1.z, w.z, fmaf(a1.w, w.w, acc1))));
            acc2 = fmaf(a2.x, w.x, fmaf(a2.y, w.y, fmaf(a2.z, w.z, fmaf(a2.w, w.w, acc2))));
            acc3 = fmaf(a3.x, w.x, fmaf(a3.y, w.y, fmaf(a3.z, w.z, fmaf(a3.w, w.w, acc3))));
        }
        if (K2 > 0) {
#pragma unroll
            for (int c = 0; c < K2 / 4; ++c) {
                float4 w = w4[K1 / 4 + c];
                float4 a0 = *reinterpret_cast<const float4*>(B + (size_t)n0 * K2 + 4 * c);
                float4 a1 = *reinterpret_cast<const float4*>(B + (size_t)n1 * K2 + 4 * c);
                float4 a2 = *reinterpret_cast<const float4*>(B + (size_t)n2 * K2 + 4 * c);
                float4 a3 = *reinterpret_cast<const float4*>(B + (size_t)n3 * K2 + 4 * c);
                acc0 = fmaf(a0.x, w.x, fmaf(a0.y, w.y, fmaf(a0.z, w.z, fmaf(a0.w, w.w, acc0))));
                acc1 = fmaf(a1.x, w.x, fmaf(a1.y, w.y, fmaf(a1.z, w.z, fmaf(a1.w, w.w, acc1))));
                acc2 = fmaf(a2.x, w.x, fmaf(a2.y, w.y, fmaf(a2.z, w.z, fmaf(a2.w, w.w, acc2))));
                acc3 = fmaf(a3.x, w.x, fmaf(a3.y, w.y, fmaf(a3.z, w.z, fmaf(a3.w, w.w, acc3))));
            }
        }
        float accs[4] = {acc0, acc1, acc2, acc3};
#pragma unroll
        for (int m = 0; m < M; ++m) {
            int n = base + m;
            if (n >= N) break;
            float acc = accs[m];
            if (RELU) acc = fmaxf(acc, 0.0f);
            if (SKIP) {
                size_t off = (size_t)n * 64 + lane;
                float r = swself * acc;
                if (nprev > 0) r = fmaf(s0, q0[off], r);
                if (nprev > 1) r = fmaf(s1, q1[off], r);
                if (nprev > 2) r = fmaf(s2, q2[off], r);
                if (nprev > 3) r = fmaf(s3, q3[off], r);
                if (nprev > 4) r = fmaf(s4, q4[off], r);
                if (nprev > 5) r = fmaf(s5, q5[off], r);
                acc = r;
            }
            out[(size_t)n * 64 + lane] = acc;
        }
    }
}

// ---------------- CSR aggregate (HID=64): wave per node, lane=feature ----------------
__global__ __launch_bounds__(256) void csr_agg_kernel(
    const int* __restrict__ rowptr, const int* __restrict__ srcp,
    const float* __restrict__ eap, const float* __restrict__ p,
    const float* __restrict__ Wme, float* __restrict__ agg, int N)
{
    int lane = threadIdx.x & 63;
    int gwave = blockIdx.x * (blockDim.x >> 6) + (threadIdx.x >> 6);
    int nw = gridDim.x * (blockDim.x >> 6);
    float w0 = Wme[0 * 64 + lane];
    float w1 = Wme[1 * 64 + lane];
    float w2 = Wme[2 * 64 + lane];
    float w3 = Wme[3 * 64 + lane];
    for (int n = gwave; n < N; n += nw) {
        int beg = rowptr[n], end = rowptr[n + 1];
        float acc = 0.0f;
        int s = 0; float4 a = {0, 0, 0, 0};
        if (beg < end) {
            s = srcp[beg];
            a = *reinterpret_cast<const float4*>(eap + (size_t)4 * beg);
        }
        for (int j = beg; j < end; ++j) {
            float v = p[(size_t)s * 64 + lane];  // issued while next s/a load
            int jn = j + 1;
            int s2 = 0; float4 a2 = {0, 0, 0, 0};
            if (jn < end) {
                s2 = srcp[jn];
                a2 = *reinterpret_cast<const float4*>(eap + (size_t)4 * jn);
            }
            v = fmaf(a.x, w0, v);
            v = fmaf(a.y, w1, v);
            v = fmaf(a.z, w2, v);
            v = fmaf(a.w, w3, v);
            acc += fmaxf(v, 0.0f);
            s = s2; a = a2;
        }
        agg[(size_t)n * 64 + lane] = acc;
    }
}

// ---------------- fallback atomic edge kernel (if ws too small for CSR) ----------------
__global__ __launch_bounds__(256) void edge_kernel(
    const int* __restrict__ ei, const float* __restrict__ ea,
    const float* __restrict__ p, const float* __restrict__ Wme,
    float* __restrict__ agg, int E)
{
    int lane = threadIdx.x & 63;
    int gwave = blockIdx.x * (blockDim.x >> 6) + (threadIdx.x >> 6);
    int nw = gridDim.x * (blockDim.x >> 6);
    float w0 = Wme[0 * 64 + lane];
    float w1 = Wme[1 * 64 + lane];
    float w2 = Wme[2 * 64 + lane];
    float w3 = Wme[3 * 64 + lane];
    for (int e = gwave; e < E; e += nw) {
        int s = ei[e];
        int d = ei[E + e];
        float4 a = *reinterpret_cast<const float4*>(ea + (size_t)4 * e);
        float v = p[(size_t)s * 64 + lane];
        v = fmaf(a.x, w0, v);
        v = fmaf(a.y, w1, v);
        v = fmaf(a.z, w2, v);
        v = fmaf(a.w, w3, v);
        v = fmaxf(v, 0.0f);
        atomicAdd(agg + (size_t)d * 64 + lane, v);
    }
}

// ---------------- last layer (OUT=4) ----------------
__global__ __launch_bounds__(256) void pl_kernel(
    const float* __restrict__ A, const float* __restrict__ W,
    const float* __restrict__ bias, float* __restrict__ out, int N)
{
    __shared__ float Wl[64 * 4];
    __shared__ float bl[4];
    for (int i = threadIdx.x; i < 256; i += blockDim.x) Wl[i] = W[i];
    if (threadIdx.x < 4) bl[threadIdx.x] = bias[threadIdx.x];
    __syncthreads();
    int t = blockIdx.x * blockDim.x + threadIdx.x;
    int nt = gridDim.x * blockDim.x;
    for (int idx = t; idx < N * 4; idx += nt) {
        int n = idx >> 2, f = idx & 3;
        float acc = bl[f];
        const float* ar = A + (size_t)n * 64;
#pragma unroll
        for (int kk = 0; kk < 16; ++kk) {
            float4 a4 = *reinterpret_cast<const float4*>(ar + 4 * kk);
            acc = fmaf(a4.x, Wl[(4 * kk + 0) * 4 + f], acc);
            acc = fmaf(a4.y, Wl[(4 * kk + 1) * 4 + f], acc);
            acc = fmaf(a4.z, Wl[(4 * kk + 2) * 4 + f], acc);
            acc = fmaf(a4.w, Wl[(4 * kk + 3) * 4 + f], acc);
        }
        out[idx] = acc;
    }
}

__global__ __launch_bounds__(256) void csr_agg4_kernel(
    const int* __restrict__ rowptr, const int* __restrict__ srcp,
    const float* __restrict__ eap, const float* __restrict__ p4,
    const float* __restrict__ Wme, float* __restrict__ agg4, int N)
{
    float w[16];
#pragma unroll
    for (int i = 0; i < 16; ++i) w[i] = Wme[i];
    int t = blockIdx.x * blockDim.x + threadIdx.x;
    int nt = gridDim.x * blockDim.x;
    for (int n = t; n < N; n += nt) {
        int beg = rowptr[n], end = rowptr[n + 1];
        float4 acc = {0, 0, 0, 0};
        for (int j = beg; j < end; ++j) {
            int s = srcp[j];
            float4 a = *reinterpret_cast<const float4*>(eap + (size_t)4 * j);
            float4 pv = *reinterpret_cast<const float4*>(p4 + (size_t)4 * s);
            float vx = pv.x + a.x * w[0] + a.y * w[4] + a.z * w[8]  + a.w * w[12];
            float vy = pv.y + a.x * w[1] + a.y * w[5] + a.z * w[9]  + a.w * w[13];
            float vz = pv.z + a.x * w[2] + a.y * w[6] + a.z * w[10] + a.w * w[14];
            float vw = pv.w + a.x * w[3] + a.y * w[7] + a.z * w[11] + a.w * w[15];
            acc.x += fmaxf(vx, 0.0f);
            acc.y += fmaxf(vy, 0.0f);
            acc.z += fmaxf(vz, 0.0f);
            acc.w += fmaxf(vw, 0.0f);
        }
        *reinterpret_cast<float4*>(agg4 + (size_t)4 * n) = acc;
    }
}

__global__ __launch_bounds__(256) void edge4_kernel(
    const int* __restrict__ ei, const float* __restrict__ ea,
    const float* __restrict__ p4, const float* __restrict__ Wme,
    float* __restrict__ agg4, int E)
{
    int lane = threadIdx.x & 63;
    int f = lane & 3;
    int gwave = blockIdx.x * (blockDim.x >> 6) + (threadIdx.x >> 6);
    int nw = gridDim.x * (blockDim.x >> 6);
    float w0 = Wme[0 * 4 + f];
    float w1 = Wme[1 * 4 + f];
    float w2 = Wme[2 * 4 + f];
    float w3 = Wme[3 * 4 + f];
    for (int e0 = gwave * 16; e0 < E; e0 += nw * 16) {
        int e = e0 + (lane >> 2);
        if (e < E) {
            int s = ei[e];
            int d = ei[E + e];
            float4 a = *reinterpret_cast<const float4*>(ea + (size_t)4 * e);
            float v = p4[(size_t)s * 4 + f];
            v = fmaf(a.x, w0, v);
            v = fmaf(a.y, w1, v);
            v = fmaf(a.z, w2, v);
            v = fmaf(a.w, w3, v);
            v = fmaxf(v, 0.0f);
            atomicAdd(agg4 + (size_t)d * 4 + f, v);
        }
    }
}

__global__ __launch_bounds__(256) void ul_kernel(
    const float* __restrict__ A, const float* __restrict__ agg4,
    const float* __restrict__ W /*[68][4]*/, const float* __restrict__ bias,
    float* __restrict__ out, int N)
{
    __shared__ float Wl[68 * 4];
    __shared__ float bl[4];
    for (int i = threadIdx.x; i < 68 * 4; i += blockDim.x) Wl[i] = W[i];
    if (threadIdx.x < 4) bl[threadIdx.x] = bias[threadIdx.x];
    __syncthreads();
    int t = blockIdx.x * blockDim.x + threadIdx.x;
    int nt = gridDim.x * blockDim.x;
    for (int idx = t; idx < N * 4; idx += nt) {
        int n = idx >> 2, f = idx & 3;
        float acc = bl[f];
        const float* ar = A + (size_t)n * 64;
#pragma unroll
        for (int kk = 0; kk < 16; ++kk) {
            float4 a4 = *reinterpret_cast<const float4*>(ar + 4 * kk);
            acc = fmaf(a4.x, Wl[(4 * kk + 0) * 4 + f], acc);
            acc = fmaf(a4.y, Wl[(4 * kk + 1) * 4 + f], acc);
            acc = fmaf(a4.z, Wl[(4 * kk + 2) * 4 + f], acc);
            acc = fmaf(a4.w, Wl[(4 * kk + 3) * 4 + f], acc);
        }
        float4 g = *reinterpret_cast<const float4*>(agg4 + (size_t)n * 4);
        acc = fmaf(g.x, Wl[(64 + 0) * 4 + f], acc);
        acc = fmaf(g.y, Wl[(64 + 1) * 4 + f], acc);
        acc = fmaf(g.z, Wl[(64 + 2) * 4 + f], acc);
        acc = fmaf(g.w, Wl[(64 + 3) * 4 + f], acc);
        out[idx] = fmaxf(acc, 0.0f);
    }
}

extern "C" void kernel_launch(void* const* d_in, const int* in_sizes, int n_in,
                              void* d_out, int out_size, void* d_ws, size_t ws_size,
                              hipStream_t stream)
{
    const float* x      = (const float*)d_in[0];
    const int*   ei     = (const int*)d_in[1];
    const float* ea     = (const float*)d_in[2];
    const float* Wm1    = (const float*)d_in[3];   // [12][64]
    const float* bm1    = (const float*)d_in[4];
    const float* Wu1    = (const float*)d_in[5];   // [72][64]
    const float* bu1    = (const float*)d_in[6];
    const float* Wm_mid = (const float*)d_in[7];   // [5][68][64]
    const float* bm_mid = (const float*)d_in[8];   // [5][64]
    const float* Wu_mid = (const float*)d_in[9];   // [5][128][64]
    const float* bu_mid = (const float*)d_in[10];  // [5][64]
    const float* WmL    = (const float*)d_in[11];  // [68][4]
    const float* bmL    = (const float*)d_in[12];
    const float* WuL    = (const float*)d_in[13];  // [68][4]
    const float* buL    = (const float*)d_in[14];
    const float* sw     = (const float*)d_in[15];  // [27]

    const int N = in_sizes[0] / 8;
    const int E = in_sizes[2] / 4;

    float* ws = (float*)d_ws;
    size_t nh = (size_t)N * 64;
    float* p    = ws;
    float* agg  = ws + nh;
    float* x1   = ws + 2 * nh;
    float* x2w  = ws + 3 * nh;
    float* x3w  = ws + 4 * nh;
    float* x4w  = ws + 5 * nh;
    float* x5w  = ws + 6 * nh;
    float* x6w  = ws + 7 * nh;
    float* x7w  = p;                  // p free after last mid edge pass
    float* p4   = agg;                // [N*4]
    float* agg4 = agg + (size_t)N * 4;

    // CSR region
    float* eap   = ws + 8 * nh;                 // [E*4]
    int*   srcp  = (int*)(eap + (size_t)E * 4); // [E]
    int*   rowptr= srcp + E;                    // [N+1]
    int*   cursor= rowptr + N + 1;              // [N] (also histogram counts)
    int*   bsum  = cursor + N;                  // [<=1024]
    size_t need_bytes = (8 * nh + (size_t)E * 4) * 4 + ((size_t)E + 2 * N + 1 + 1024) * 4;
    bool use_csr = ws_size >= need_bytes;

    dim3 blk(256);
    dim3 gLin(1024), gEdge(2048), g4(1024);
    const float* nul = nullptr;

    if (use_csr) {
        int B = (N + 1023) / 1024;
        hipMemsetAsync(cursor, 0, (size_t)N * 4, stream);
        hist_kernel<<<gEdge, blk, 0, stream>>>(ei, cursor, E);
        scan1_kernel<<<dim3(B), blk, 0, stream>>>(cursor, rowptr, bsum, N);
        scan2_kernel<<<dim3(1), blk, 0, stream>>>(bsum, B);
        scan3_kernel<<<dim3(256), blk, 0, stream>>>(rowptr, cursor, bsum, N, E);
        scatter_kernel<<<gEdge, blk, 0, stream>>>(ei, ea, cursor, srcp, eap, E);
    }

    // per-layer edge pass helper (CSR or atomic fallback)
    auto edge_pass = [&](const float* pp, const float* Wme, float* aggout) {
        if (use_csr) {
            csr_agg_kernel<<<gEdge, blk, 0, stream>>>(rowptr, srcp, eap, pp, Wme, aggout, N);
        } else {
            hipMemsetAsync(aggout, 0, nh * sizeof(float), stream);
            edge_kernel<<<gEdge, blk, 0, stream>>>(ei, ea, pp, Wme, aggout, E);
        }
    };

    // ---- layer 1 ----
    lin_kernel<8, 0, false, false><<<gLin, blk, 0, stream>>>(
        x, nul, Wm1, bm1, p, N, nul, nul, nul, nul, nul, nul, sw, 0, 0);
    edge_pass(p, Wm1 + 8 * 64, agg);
    lin_kernel<8, 64, true, false><<<gLin, blk, 0, stream>>>(
        x, agg, Wu1, bu1, x1, N, nul, nul, nul, nul, nul, nul, sw, 0, 0);

    // ---- mid layers ----
    struct MidStep {
        int mi; const float* in; float* out; int swbase; int nprev;
        const float *q0, *q1, *q2, *q3, *q4, *q5;
    };
    MidStep steps[6] = {
        {0, x1,  x2w, 0,  1, x1,  nul, nul, nul, nul, nul},
        {1, x2w, x3w, 2,  2, x1,  x2w, nul, nul, nul, nul},
        {2, x3w, x4w, 5,  3, x1,  x2w, x3w, nul, nul, nul},
        {2, x4w, x5w, 9,  4, x1,  x2w, x3w, x4w, nul, nul},  // reuses mid layer 2 (faithful to bug)
        {3, x5w, x6w, 14, 5, x1,  x2w, x3w, x4w, x5w, nul},
        {4, x6w, x7w, 20, 6, x1,  x2w, x3w, x4w, x5w, x6w},
    };
    for (int li = 0; li < 6; ++li) {
        const MidStep& st = steps[li];
        const float* Wm = Wm_mid + (size_t)st.mi * 68 * 64;
        const float* bm = bm_mid + (size_t)st.mi * 64;
        const float* Wu = Wu_mid + (size_t)st.mi * 128 * 64;
        const float* bu = bu_mid + (size_t)st.mi * 64;
        lin_kernel<64, 0, false, false><<<gLin, blk, 0, stream>>>(
            st.in, nul, Wm, bm, p, N, nul, nul, nul, nul, nul, nul, sw, 0, 0);
        edge_pass(p, Wm + 64 * 64, agg);
        lin_kernel<64, 64, true, true><<<gLin, blk, 0, stream>>>(
            st.in, agg, Wu, bu, st.out, N,
            st.q0, st.q1, st.q2, st.q3, st.q4, st.q5, sw, st.swbase, st.nprev);
    }

    // ---- last layer (OUT=4) ----
    pl_kernel<<<g4, blk, 0, stream>>>(x7w, WmL, bmL, p4, N);
    if (use_csr) {
        csr_agg4_kernel<<<g4, blk, 0, stream>>>(rowptr, srcp, eap, p4, WmL + 64 * 4, agg4, N);
    } else {
        hipMemsetAsync(agg4, 0, (size_t)N * 4 * sizeof(float), stream);
        edge4_kernel<<<gEdge, blk, 0, stream>>>(ei, ea, p4, WmL + 64 * 4, agg4, E);
    }
    ul_kernel<<<g4, blk, 0, stream>>>(x7w, agg4, WuL, buL, (float*)d_out, N);
}

// Round 3
// 1371.720 us; speedup vs baseline: 2.8491x; 2.3625x over previous
//
#include <hip/hip_runtime.h>

// GNN: 8 graph layers (message -> segment_sum -> update) + skip combos.
// m_e = ReLU(p[src] + ea_e @ Wme), p = h @ Wmh + bm (bias folded into p).
// Aggregation via CSR-by-dst (built once per launch) -> register accumulate.
// Node linears: register-tiled GEMM, 64x64 tile per 256-thread block,
// 4x4 acc per thread, A-chunk transposed in LDS (stride 68 -> aligned b128,
// conflict-free), W-chunk in LDS.

#define WAVE 64

// ---------------- CSR build ----------------
__global__ __launch_bounds__(256) void hist_kernel(
    const int* __restrict__ ei, int* __restrict__ cnt, int E)
{
    int t = blockIdx.x * blockDim.x + threadIdx.x;
    int nt = gridDim.x * blockDim.x;
    for (int e = t; e < E; e += nt) atomicAdd(&cnt[ei[E + e]], 1);
}

__global__ __launch_bounds__(256) void scan1_kernel(
    const int* __restrict__ cnt, int* __restrict__ out, int* __restrict__ bsum, int N)
{
    __shared__ int lds[256];
    int t = threadIdx.x;
    int base = blockIdx.x * 1024 + t * 4;
    int v0 = (base + 0 < N) ? cnt[base + 0] : 0;
    int v1 = (base + 1 < N) ? cnt[base + 1] : 0;
    int v2 = (base + 2 < N) ? cnt[base + 2] : 0;
    int v3 = (base + 3 < N) ? cnt[base + 3] : 0;
    int tsum = v0 + v1 + v2 + v3;
    lds[t] = tsum;
    __syncthreads();
    for (int off = 1; off < 256; off <<= 1) {
        int x = 0;
        if (t >= off) x = lds[t - off];
        __syncthreads();
        if (t >= off) lds[t] += x;
        __syncthreads();
    }
    int run = lds[t] - tsum;  // exclusive
    if (base + 0 < N) out[base + 0] = run; run += v0;
    if (base + 1 < N) out[base + 1] = run; run += v1;
    if (base + 2 < N) out[base + 2] = run; run += v2;
    if (base + 3 < N) out[base + 3] = run;
    if (t == 255) bsum[blockIdx.x] = lds[255];
}

__global__ __launch_bounds__(256) void scan2_kernel(int* __restrict__ bsum, int B)
{
    __shared__ int lds[256];
    __shared__ int carry;
    int t = threadIdx.x;
    if (t == 0) carry = 0;
    __syncthreads();
    for (int start = 0; start < B; start += 256) {
        int i = start + t;
        int v = (i < B) ? bsum[i] : 0;
        lds[t] = v;
        __syncthreads();
        for (int off = 1; off < 256; off <<= 1) {
            int x = 0;
            if (t >= off) x = lds[t - off];
            __syncthreads();
            if (t >= off) lds[t] += x;
            __syncthreads();
        }
        if (i < B) bsum[i] = carry + lds[t] - v;  // exclusive
        __syncthreads();
        if (t == 255) carry += lds[255];
        __syncthreads();
    }
}

__global__ __launch_bounds__(256) void scan3_kernel(
    int* __restrict__ rowptr, int* __restrict__ cursor,
    const int* __restrict__ bsum, int N, int E)
{
    int t = blockIdx.x * blockDim.x + threadIdx.x;
    int nt = gridDim.x * blockDim.x;
    for (int i = t; i < N; i += nt) {
        int v = rowptr[i] + bsum[i >> 10];
        rowptr[i] = v;
        cursor[i] = v;
    }
    if (t == 0) rowptr[N] = E;
}

__global__ __launch_bounds__(256) void scatter_kernel(
    const int* __restrict__ ei, const float* __restrict__ ea,
    int* __restrict__ cursor, int* __restrict__ srcp, float* __restrict__ eap, int E)
{
    int t = blockIdx.x * blockDim.x + threadIdx.x;
    int nt = gridDim.x * blockDim.x;
    for (int e = t; e < E; e += nt) {
        int d = ei[E + e];
        int pos = atomicAdd(&cursor[d], 1);
        srcp[pos] = ei[e];
        *reinterpret_cast<float4*>(eap + (size_t)4 * pos) =
            *reinterpret_cast<const float4*>(ea + (size_t)4 * e);
    }
}

// ---------------- register-tiled node linear ----------------
// 64 nodes x 64 features per 256-thread block; thread (tx,ty) owns 4x4.
// As[k][node] transposed chunk, stride 68 floats (16B-aligned rows, pad 4).
// Ws[k][64] chunk.

template<int C>
__device__ __forceinline__ void stage_chunk(
    const float* __restrict__ src, int rs, int co, int base, int N,
    const float* __restrict__ Wg, int t, float* As, float* Ws)
{
    // W chunk: C rows x 64 cols, contiguous copy
    {
        const float4* wsrc = reinterpret_cast<const float4*>(Wg + (size_t)co * 64);
        float4* wdst = reinterpret_cast<float4*>(Ws);
        for (int idx = t; idx < C * 16; idx += 256) wdst[idx] = wsrc[idx];
    }
    // A chunk transposed: As[k][n] = src[base+n][co+k]
    constexpr int NFQ = C / 4;
    for (int idx = t; idx < 64 * NFQ; idx += 256) {
        int n = idx / NFQ, kq = idx % NFQ;
        int gn = min(base + n, N - 1);
        float4 v = *reinterpret_cast<const float4*>(src + (size_t)gn * rs + co + 4 * kq);
        As[(4 * kq + 0) * 68 + n] = v.x;
        As[(4 * kq + 1) * 68 + n] = v.y;
        As[(4 * kq + 2) * 68 + n] = v.z;
        As[(4 * kq + 3) * 68 + n] = v.w;
    }
}

template<int C>
__device__ __forceinline__ void compute_chunk(
    const float* As, const float* Ws, int tx, int ty, float acc[4][4])
{
#pragma unroll
    for (int k = 0; k < C; ++k) {
        float4 a4 = *reinterpret_cast<const float4*>(As + k * 68 + 4 * ty);
        float4 w4 = *reinterpret_cast<const float4*>(Ws + k * 64 + 4 * tx);
        float av[4] = {a4.x, a4.y, a4.z, a4.w};
        float wv[4] = {w4.x, w4.y, w4.z, w4.w};
#pragma unroll
        for (int i = 0; i < 4; ++i)
#pragma unroll
            for (int j = 0; j < 4; ++j)
                acc[i][j] = fmaf(av[i], wv[j], acc[i][j]);
    }
}

template<int K1, int K2, bool RELU, bool SKIP>
__global__ __launch_bounds__(256) void lin_kernel(
    const float* __restrict__ A, const float* __restrict__ B,
    const float* __restrict__ W, const float* __restrict__ bias,
    float* __restrict__ out, int N,
    const float* __restrict__ q0, const float* __restrict__ q1,
    const float* __restrict__ q2, const float* __restrict__ q3,
    const float* __restrict__ q4, const float* __restrict__ q5,
    const float* __restrict__ sw, int swbase, int nprev)
{
    __shared__ float As[32 * 68];
    __shared__ float Ws[32 * 64];
    int t = threadIdx.x;
    int tx = t & 15, ty = t >> 4;
    int base = blockIdx.x * 64;

    float acc[4][4];
    {
        float4 bv = *reinterpret_cast<const float4*>(bias + 4 * tx);
#pragma unroll
        for (int i = 0; i < 4; ++i) {
            acc[i][0] = bv.x; acc[i][1] = bv.y; acc[i][2] = bv.z; acc[i][3] = bv.w;
        }
    }

    constexpr int C1 = (K1 < 32) ? K1 : 32;
    for (int co = 0; co < K1; co += C1) {
        __syncthreads();
        stage_chunk<C1>(A, K1, co, base, N, W, t, As, Ws);
        __syncthreads();
        compute_chunk<C1>(As, Ws, tx, ty, acc);
    }
    if constexpr (K2 > 0) {
        constexpr int C2 = (K2 < 32) ? K2 : 32;
        for (int co = 0; co < K2; co += C2) {
            __syncthreads();
            stage_chunk<C2>(B, K2, co, base, N, W + (size_t)K1 * 64, t, As, Ws);
            __syncthreads();
            compute_chunk<C2>(As, Ws, tx, ty, acc);
        }
    }

    float swself = 1.0f, s[6] = {0, 0, 0, 0, 0, 0};
    if (SKIP) {
        swself = sw[swbase + nprev];
        for (int j = 0; j < nprev; ++j) s[j] = sw[swbase + j];
    }
    const float* qs[6] = {q0, q1, q2, q3, q4, q5};

#pragma unroll
    for (int i = 0; i < 4; ++i) {
        int gn = base + 4 * ty + i;
        if (gn < N) {
            float r0 = acc[i][0], r1 = acc[i][1], r2 = acc[i][2], r3 = acc[i][3];
            if (RELU) {
                r0 = fmaxf(r0, 0.0f); r1 = fmaxf(r1, 0.0f);
                r2 = fmaxf(r2, 0.0f); r3 = fmaxf(r3, 0.0f);
            }
            if (SKIP) {
                r0 *= swself; r1 *= swself; r2 *= swself; r3 *= swself;
                for (int j = 0; j < nprev; ++j) {
                    float4 qv = *reinterpret_cast<const float4*>(qs[j] + (size_t)gn * 64 + 4 * tx);
                    r0 = fmaf(s[j], qv.x, r0);
                    r1 = fmaf(s[j], qv.y, r1);
                    r2 = fmaf(s[j], qv.z, r2);
                    r3 = fmaf(s[j], qv.w, r3);
                }
            }
            float4 r; r.x = r0; r.y = r1; r.z = r2; r.w = r3;
            *reinterpret_cast<float4*>(out + (size_t)gn * 64 + 4 * tx) = r;
        }
    }
}

// ---------------- CSR aggregate (HID=64): wave per node, lane=feature ----------------
// 2-deep prefetch on srcp/eap, 1-deep on the p-row gather.
__global__ __launch_bounds__(256) void csr_agg_kernel(
    const int* __restrict__ rowptr, const int* __restrict__ srcp,
    const float* __restrict__ eap, const float* __restrict__ p,
    const float* __restrict__ Wme, float* __restrict__ agg, int N)
{
    int lane = threadIdx.x & 63;
    int gwave = blockIdx.x * (blockDim.x >> 6) + (threadIdx.x >> 6);
    int nw = gridDim.x * (blockDim.x >> 6);
    float w0 = Wme[0 * 64 + lane];
    float w1 = Wme[1 * 64 + lane];
    float w2 = Wme[2 * 64 + lane];
    float w3 = Wme[3 * 64 + lane];
    for (int n = gwave; n < N; n += nw) {
        int beg = rowptr[n], end = rowptr[n + 1];
        float acc = 0.0f;
        float vA = 0.0f; float4 aA = {0, 0, 0, 0};
        int sB = 0;      float4 aB = {0, 0, 0, 0};
        if (beg < end) {
            int sA = srcp[beg];
            aA = *reinterpret_cast<const float4*>(eap + (size_t)4 * beg);
            vA = p[(size_t)sA * 64 + lane];
        }
        if (beg + 1 < end) {
            sB = srcp[beg + 1];
            aB = *reinterpret_cast<const float4*>(eap + (size_t)4 * (beg + 1));
        }
        for (int j = beg; j < end; ++j) {
            float vB = 0.0f;
            if (j + 1 < end) vB = p[(size_t)sB * 64 + lane];
            int sC = 0; float4 aC = {0, 0, 0, 0};
            if (j + 2 < end) {
                sC = srcp[j + 2];
                aC = *reinterpret_cast<const float4*>(eap + (size_t)4 * (j + 2));
            }
            float m = vA;
            m = fmaf(aA.x, w0, m);
            m = fmaf(aA.y, w1, m);
            m = fmaf(aA.z, w2, m);
            m = fmaf(aA.w, w3, m);
            acc += fmaxf(m, 0.0f);
            vA = vB; aA = aB; sB = sC; aB = aC;
        }
        agg[(size_t)n * 64 + lane] = acc;
    }
}

// ---------------- fallback atomic edge kernel ----------------
__global__ __launch_bounds__(256) void edge_kernel(
    const int* __restrict__ ei, const float* __restrict__ ea,
    const float* __restrict__ p, const float* __restrict__ Wme,
    float* __restrict__ agg, int E)
{
    int lane = threadIdx.x & 63;
    int gwave = blockIdx.x * (blockDim.x >> 6) + (threadIdx.x >> 6);
    int nw = gridDim.x * (blockDim.x >> 6);
    float w0 = Wme[0 * 64 + lane];
    float w1 = Wme[1 * 64 + lane];
    float w2 = Wme[2 * 64 + lane];
    float w3 = Wme[3 * 64 + lane];
    for (int e = gwave; e < E; e += nw) {
        int s = ei[e];
        int d = ei[E + e];
        float4 a = *reinterpret_cast<const float4*>(ea + (size_t)4 * e);
        float v = p[(size_t)s * 64 + lane];
        v = fmaf(a.x, w0, v);
        v = fmaf(a.y, w1, v);
        v = fmaf(a.z, w2, v);
        v = fmaf(a.w, w3, v);
        v = fmaxf(v, 0.0f);
        atomicAdd(agg + (size_t)d * 64 + lane, v);
    }
}

// ---------------- last layer (OUT=4) ----------------
__global__ __launch_bounds__(256) void pl_kernel(
    const float* __restrict__ A, const float* __restrict__ W,
    const float* __restrict__ bias, float* __restrict__ out, int N)
{
    __shared__ float Wl[64 * 4];
    __shared__ float bl[4];
    for (int i = threadIdx.x; i < 256; i += blockDim.x) Wl[i] = W[i];
    if (threadIdx.x < 4) bl[threadIdx.x] = bias[threadIdx.x];
    __syncthreads();
    int t = blockIdx.x * blockDim.x + threadIdx.x;
    int nt = gridDim.x * blockDim.x;
    for (int idx = t; idx < N * 4; idx += nt) {
        int n = idx >> 2, f = idx & 3;
        float acc = bl[f];
        const float* ar = A + (size_t)n * 64;
#pragma unroll
        for (int kk = 0; kk < 16; ++kk) {
            float4 a4 = *reinterpret_cast<const float4*>(ar + 4 * kk);
            acc = fmaf(a4.x, Wl[(4 * kk + 0) * 4 + f], acc);
            acc = fmaf(a4.y, Wl[(4 * kk + 1) * 4 + f], acc);
            acc = fmaf(a4.z, Wl[(4 * kk + 2) * 4 + f], acc);
            acc = fmaf(a4.w, Wl[(4 * kk + 3) * 4 + f], acc);
        }
        out[idx] = acc;
    }
}

__global__ __launch_bounds__(256) void csr_agg4_kernel(
    const int* __restrict__ rowptr, const int* __restrict__ srcp,
    const float* __restrict__ eap, const float* __restrict__ p4,
    const float* __restrict__ Wme, float* __restrict__ agg4, int N)
{
    float w[16];
#pragma unroll
    for (int i = 0; i < 16; ++i) w[i] = Wme[i];
    int t = blockIdx.x * blockDim.x + threadIdx.x;
    int nt = gridDim.x * blockDim.x;
    for (int n = t; n < N; n += nt) {
        int beg = rowptr[n], end = rowptr[n + 1];
        float4 acc = {0, 0, 0, 0};
        for (int j = beg; j < end; ++j) {
            int s = srcp[j];
            float4 a = *reinterpret_cast<const float4*>(eap + (size_t)4 * j);
            float4 pv = *reinterpret_cast<const float4*>(p4 + (size_t)4 * s);
            float vx = pv.x + a.x * w[0] + a.y * w[4] + a.z * w[8]  + a.w * w[12];
            float vy = pv.y + a.x * w[1] + a.y * w[5] + a.z * w[9]  + a.w * w[13];
            float vz = pv.z + a.x * w[2] + a.y * w[6] + a.z * w[10] + a.w * w[14];
            float vw = pv.w + a.x * w[3] + a.y * w[7] + a.z * w[11] + a.w * w[15];
            acc.x += fmaxf(vx, 0.0f);
            acc.y += fmaxf(vy, 0.0f);
            acc.z += fmaxf(vz, 0.0f);
            acc.w += fmaxf(vw, 0.0f);
        }
        *reinterpret_cast<float4*>(agg4 + (size_t)4 * n) = acc;
    }
}

__global__ __launch_bounds__(256) void edge4_kernel(
    const int* __restrict__ ei, const float* __restrict__ ea,
    const float* __restrict__ p4, const float* __restrict__ Wme,
    float* __restrict__ agg4, int E)
{
    int lane = threadIdx.x & 63;
    int f = lane & 3;
    int gwave = blockIdx.x * (blockDim.x >> 6) + (threadIdx.x >> 6);
    int nw = gridDim.x * (blockDim.x >> 6);
    float w0 = Wme[0 * 4 + f];
    float w1 = Wme[1 * 4 + f];
    float w2 = Wme[2 * 4 + f];
    float w3 = Wme[3 * 4 + f];
    for (int e0 = gwave * 16; e0 < E; e0 += nw * 16) {
        int e = e0 + (lane >> 2);
        if (e < E) {
            int s = ei[e];
            int d = ei[E + e];
            float4 a = *reinterpret_cast<const float4*>(ea + (size_t)4 * e);
            float v = p4[(size_t)s * 4 + f];
            v = fmaf(a.x, w0, v);
            v = fmaf(a.y, w1, v);
            v = fmaf(a.z, w2, v);
            v = fmaf(a.w, w3, v);
            v = fmaxf(v, 0.0f);
            atomicAdd(agg4 + (size_t)d * 4 + f, v);
        }
    }
}

__global__ __launch_bounds__(256) void ul_kernel(
    const float* __restrict__ A, const float* __restrict__ agg4,
    const float* __restrict__ W /*[68][4]*/, const float* __restrict__ bias,
    float* __restrict__ out, int N)
{
    __shared__ float Wl[68 * 4];
    __shared__ float bl[4];
    for (int i = threadIdx.x; i < 68 * 4; i += blockDim.x) Wl[i] = W[i];
    if (threadIdx.x < 4) bl[threadIdx.x] = bias[threadIdx.x];
    __syncthreads();
    int t = blockIdx.x * blockDim.x + threadIdx.x;
    int nt = gridDim.x * blockDim.x;
    for (int idx = t; idx < N * 4; idx += nt) {
        int n = idx >> 2, f = idx & 3;
        float acc = bl[f];
        const float* ar = A + (size_t)n * 64;
#pragma unroll
        for (int kk = 0; kk < 16; ++kk) {
            float4 a4 = *reinterpret_cast<const float4*>(ar + 4 * kk);
            acc = fmaf(a4.x, Wl[(4 * kk + 0) * 4 + f], acc);
            acc = fmaf(a4.y, Wl[(4 * kk + 1) * 4 + f], acc);
            acc = fmaf(a4.z, Wl[(4 * kk + 2) * 4 + f], acc);
            acc = fmaf(a4.w, Wl[(4 * kk + 3) * 4 + f], acc);
        }
        float4 g = *reinterpret_cast<const float4*>(agg4 + (size_t)n * 4);
        acc = fmaf(g.x, Wl[(64 + 0) * 4 + f], acc);
        acc = fmaf(g.y, Wl[(64 + 1) * 4 + f], acc);
        acc = fmaf(g.z, Wl[(64 + 2) * 4 + f], acc);
        acc = fmaf(g.w, Wl[(64 + 3) * 4 + f], acc);
        out[idx] = fmaxf(acc, 0.0f);
    }
}

extern "C" void kernel_launch(void* const* d_in, const int* in_sizes, int n_in,
                              void* d_out, int out_size, void* d_ws, size_t ws_size,
                              hipStream_t stream)
{
    const float* x      = (const float*)d_in[0];
    const int*   ei     = (const int*)d_in[1];
    const float* ea     = (const float*)d_in[2];
    const float* Wm1    = (const float*)d_in[3];   // [12][64]
    const float* bm1    = (const float*)d_in[4];
    const float* Wu1    = (const float*)d_in[5];   // [72][64]
    const float* bu1    = (const float*)d_in[6];
    const float* Wm_mid = (const float*)d_in[7];   // [5][68][64]
    const float* bm_mid = (const float*)d_in[8];   // [5][64]
    const float* Wu_mid = (const float*)d_in[9];   // [5][128][64]
    const float* bu_mid = (const float*)d_in[10];  // [5][64]
    const float* WmL    = (const float*)d_in[11];  // [68][4]
    const float* bmL    = (const float*)d_in[12];
    const float* WuL    = (const float*)d_in[13];  // [68][4]
    const float* buL    = (const float*)d_in[14];
    const float* sw     = (const float*)d_in[15];  // [27]

    const int N = in_sizes[0] / 8;
    const int E = in_sizes[2] / 4;

    float* ws = (float*)d_ws;
    size_t nh = (size_t)N * 64;
    float* p    = ws;
    float* agg  = ws + nh;
    float* x1   = ws + 2 * nh;
    float* x2w  = ws + 3 * nh;
    float* x3w  = ws + 4 * nh;
    float* x4w  = ws + 5 * nh;
    float* x5w  = ws + 6 * nh;
    float* x6w  = ws + 7 * nh;
    float* x7w  = p;                  // p free after last mid edge pass
    float* p4   = agg;                // [N*4]
    float* agg4 = agg + (size_t)N * 4;

    // CSR region
    float* eap   = ws + 8 * nh;                 // [E*4]
    int*   srcp  = (int*)(eap + (size_t)E * 4); // [E]
    int*   rowptr= srcp + E;                    // [N+1]
    int*   cursor= rowptr + N + 1;              // [N]
    int*   bsum  = cursor + N;                  // [<=1024]
    size_t need_bytes = (8 * nh + (size_t)E * 4) * 4 + ((size_t)E + 2 * N + 1 + 1024) * 4;
    bool use_csr = ws_size >= need_bytes;

    dim3 blk(256);
    dim3 gEdge(2048), g4(1024);
    dim3 gLin((N + 63) / 64);
    const float* nul = nullptr;

    if (use_csr) {
        int B = (N + 1023) / 1024;
        hipMemsetAsync(cursor, 0, (size_t)N * 4, stream);
        hist_kernel<<<gEdge, blk, 0, stream>>>(ei, cursor, E);
        scan1_kernel<<<dim3(B), blk, 0, stream>>>(cursor, rowptr, bsum, N);
        scan2_kernel<<<dim3(1), blk, 0, stream>>>(bsum, B);
        scan3_kernel<<<dim3(256), blk, 0, stream>>>(rowptr, cursor, bsum, N, E);
        scatter_kernel<<<gEdge, blk, 0, stream>>>(ei, ea, cursor, srcp, eap, E);
    }

    auto edge_pass = [&](const float* pp, const float* Wme, float* aggout) {
        if (use_csr) {
            csr_agg_kernel<<<gEdge, blk, 0, stream>>>(rowptr, srcp, eap, pp, Wme, aggout, N);
        } else {
            hipMemsetAsync(aggout, 0, nh * sizeof(float), stream);
            edge_kernel<<<gEdge, blk, 0, stream>>>(ei, ea, pp, Wme, aggout, E);
        }
    };

    // ---- layer 1 ----
    lin_kernel<8, 0, false, false><<<gLin, blk, 0, stream>>>(
        x, nul, Wm1, bm1, p, N, nul, nul, nul, nul, nul, nul, sw, 0, 0);
    edge_pass(p, Wm1 + 8 * 64, agg);
    lin_kernel<8, 64, true, false><<<gLin, blk, 0, stream>>>(
        x, agg, Wu1, bu1, x1, N, nul, nul, nul, nul, nul, nul, sw, 0, 0);

    // ---- mid layers ----
    struct MidStep {
        int mi; const float* in; float* out; int swbase; int nprev;
        const float *q0, *q1, *q2, *q3, *q4, *q5;
    };
    MidStep steps[6] = {
        {0, x1,  x2w, 0,  1, x1,  nul, nul, nul, nul, nul},
        {1, x2w, x3w, 2,  2, x1,  x2w, nul, nul, nul, nul},
        {2, x3w, x4w, 5,  3, x1,  x2w, x3w, nul, nul, nul},
        {2, x4w, x5w, 9,  4, x1,  x2w, x3w, x4w, nul, nul},  // reuses mid layer 2 (faithful to bug)
        {3, x5w, x6w, 14, 5, x1,  x2w, x3w, x4w, x5w, nul},
        {4, x6w, x7w, 20, 6, x1,  x2w, x3w, x4w, x5w, x6w},
    };
    for (int li = 0; li < 6; ++li) {
        const MidStep& st = steps[li];
        const float* Wm = Wm_mid + (size_t)st.mi * 68 * 64;
        const float* bm = bm_mid + (size_t)st.mi * 64;
        const float* Wu = Wu_mid + (size_t)st.mi * 128 * 64;
        const float* bu = bu_mid + (size_t)st.mi * 64;
        lin_kernel<64, 0, false, false><<<gLin, blk, 0, stream>>>(
            st.in, nul, Wm, bm, p, N, nul, nul, nul, nul, nul, nul, sw, 0, 0);
        edge_pass(p, Wm + 64 * 64, agg);
        lin_kernel<64, 64, true, true><<<gLin, blk, 0, stream>>>(
            st.in, agg, Wu, bu, st.out, N,
            st.q0, st.q1, st.q2, st.q3, st.q4, st.q5, sw, st.swbase, st.nprev);
    }

    // ---- last layer (OUT=4) ----
    pl_kernel<<<g4, blk, 0, stream>>>(x7w, WmL, bmL, p4, N);
    if (use_csr) {
        csr_agg4_kernel<<<g4, blk, 0, stream>>>(rowptr, srcp, eap, p4, WmL + 64 * 4, agg4, N);
    } else {
        hipMemsetAsync(agg4, 0, (size_t)N * 4 * sizeof(float), stream);
        edge4_kernel<<<gEdge, blk, 0, stream>>>(ei, ea, p4, WmL + 64 * 4, agg4, E);
    }
    ul_kernel<<<g4, blk, 0, stream>>>(x7w, agg4, WuL, buL, (float*)d_out, N);
}

// Round 4
// 1360.237 us; speedup vs baseline: 2.8732x; 1.0084x over previous
//
#include <hip/hip_runtime.h>

// GNN: 8 graph layers (message -> segment_sum -> update) + skip combos.
// m_e = ReLU(p[src] + ea_e @ Wme), p = h @ Wmh + bm (bias folded into p).
// CSR-by-dst built once per launch; aggregation gathers p rows with 4-edge
// lane groups (16 lanes x float4 = one 256B row per group) and a 2-deep
// chunk pipeline. Update linear fused with next layer's message linear
// (output tile re-used from LDS for the second GEMM).

#define WAVE 64

// ---------------- CSR build ----------------
__global__ __launch_bounds__(256) void hist_kernel(
    const int* __restrict__ ei, int* __restrict__ cnt, int E)
{
    int t = blockIdx.x * blockDim.x + threadIdx.x;
    int nt = gridDim.x * blockDim.x;
    for (int e = t; e < E; e += nt) atomicAdd(&cnt[ei[E + e]], 1);
}

__global__ __launch_bounds__(256) void scan1_kernel(
    const int* __restrict__ cnt, int* __restrict__ out, int* __restrict__ bsum, int N)
{
    __shared__ int lds[256];
    int t = threadIdx.x;
    int base = blockIdx.x * 1024 + t * 4;
    int v0 = (base + 0 < N) ? cnt[base + 0] : 0;
    int v1 = (base + 1 < N) ? cnt[base + 1] : 0;
    int v2 = (base + 2 < N) ? cnt[base + 2] : 0;
    int v3 = (base + 3 < N) ? cnt[base + 3] : 0;
    int tsum = v0 + v1 + v2 + v3;
    lds[t] = tsum;
    __syncthreads();
    for (int off = 1; off < 256; off <<= 1) {
        int x = 0;
        if (t >= off) x = lds[t - off];
        __syncthreads();
        if (t >= off) lds[t] += x;
        __syncthreads();
    }
    int run = lds[t] - tsum;  // exclusive
    if (base + 0 < N) out[base + 0] = run; run += v0;
    if (base + 1 < N) out[base + 1] = run; run += v1;
    if (base + 2 < N) out[base + 2] = run; run += v2;
    if (base + 3 < N) out[base + 3] = run;
    if (t == 255) bsum[blockIdx.x] = lds[255];
}

__global__ __launch_bounds__(256) void scan2_kernel(int* __restrict__ bsum, int B)
{
    __shared__ int lds[256];
    __shared__ int carry;
    int t = threadIdx.x;
    if (t == 0) carry = 0;
    __syncthreads();
    for (int start = 0; start < B; start += 256) {
        int i = start + t;
        int v = (i < B) ? bsum[i] : 0;
        lds[t] = v;
        __syncthreads();
        for (int off = 1; off < 256; off <<= 1) {
            int x = 0;
            if (t >= off) x = lds[t - off];
            __syncthreads();
            if (t >= off) lds[t] += x;
            __syncthreads();
        }
        if (i < B) bsum[i] = carry + lds[t] - v;  // exclusive
        __syncthreads();
        if (t == 255) carry += lds[255];
        __syncthreads();
    }
}

__global__ __launch_bounds__(256) void scan3_kernel(
    int* __restrict__ rowptr, int* __restrict__ cursor,
    const int* __restrict__ bsum, int N, int E)
{
    int t = blockIdx.x * blockDim.x + threadIdx.x;
    int nt = gridDim.x * blockDim.x;
    for (int i = t; i < N; i += nt) {
        int v = rowptr[i] + bsum[i >> 10];
        rowptr[i] = v;
        cursor[i] = v;
    }
    if (t == 0) rowptr[N] = E;
}

__global__ __launch_bounds__(256) void scatter_kernel(
    const int* __restrict__ ei, const float* __restrict__ ea,
    int* __restrict__ cursor, int* __restrict__ srcp, float* __restrict__ eap, int E)
{
    int t = blockIdx.x * blockDim.x + threadIdx.x;
    int nt = gridDim.x * blockDim.x;
    for (int e = t; e < E; e += nt) {
        int d = ei[E + e];
        int pos = atomicAdd(&cursor[d], 1);
        srcp[pos] = ei[e];
        *reinterpret_cast<float4*>(eap + (size_t)4 * pos) =
            *reinterpret_cast<const float4*>(ea + (size_t)4 * e);
    }
}

// ---------------- GEMM helpers (64x64 tile, 4x4 per thread) ----------------
template<int C>
__device__ __forceinline__ void stage_chunk(
    const float* __restrict__ src, int rs, int co, int base, int N,
    const float* __restrict__ Wg, int t, float* As, float* Ws)
{
    {
        const float4* wsrc = reinterpret_cast<const float4*>(Wg + (size_t)co * 64);
        float4* wdst = reinterpret_cast<float4*>(Ws);
        for (int idx = t; idx < C * 16; idx += 256) wdst[idx] = wsrc[idx];
    }
    constexpr int NFQ = C / 4;
    for (int idx = t; idx < 64 * NFQ; idx += 256) {
        int n = idx / NFQ, kq = idx % NFQ;
        int gn = min(base + n, N - 1);
        float4 v = *reinterpret_cast<const float4*>(src + (size_t)gn * rs + co + 4 * kq);
        As[(4 * kq + 0) * 68 + n] = v.x;
        As[(4 * kq + 1) * 68 + n] = v.y;
        As[(4 * kq + 2) * 68 + n] = v.z;
        As[(4 * kq + 3) * 68 + n] = v.w;
    }
}

template<int C>
__device__ __forceinline__ void compute_chunk(
    const float* As, const float* Ws, int tx, int ty, float acc[4][4])
{
#pragma unroll
    for (int k = 0; k < C; ++k) {
        float4 a4 = *reinterpret_cast<const float4*>(As + k * 68 + 4 * ty);
        float4 w4 = *reinterpret_cast<const float4*>(Ws + k * 64 + 4 * tx);
        float av[4] = {a4.x, a4.y, a4.z, a4.w};
        float wv[4] = {w4.x, w4.y, w4.z, w4.w};
#pragma unroll
        for (int i = 0; i < 4; ++i)
#pragma unroll
            for (int j = 0; j < 4; ++j)
                acc[i][j] = fmaf(av[i], wv[j], acc[i][j]);
    }
}

// ---------------- plain node linear (layer-1 message only) ----------------
template<int K1>
__global__ __launch_bounds__(256) void lin_kernel(
    const float* __restrict__ A, const float* __restrict__ W,
    const float* __restrict__ bias, float* __restrict__ out, int N)
{
    __shared__ float As[32 * 68];
    __shared__ float Ws[32 * 64];
    int t = threadIdx.x;
    int tx = t & 15, ty = t >> 4;
    int base = blockIdx.x * 64;

    float acc[4][4];
    {
        float4 bv = *reinterpret_cast<const float4*>(bias + 4 * tx);
#pragma unroll
        for (int i = 0; i < 4; ++i) {
            acc[i][0] = bv.x; acc[i][1] = bv.y; acc[i][2] = bv.z; acc[i][3] = bv.w;
        }
    }
    constexpr int C1 = (K1 < 32) ? K1 : 32;
    for (int co = 0; co < K1; co += C1) {
        __syncthreads();
        stage_chunk<C1>(A, K1, co, base, N, W, t, As, Ws);
        __syncthreads();
        compute_chunk<C1>(As, Ws, tx, ty, acc);
    }
#pragma unroll
    for (int i = 0; i < 4; ++i) {
        int gn = base + 4 * ty + i;
        if (gn < N) {
            float4 r; r.x = acc[i][0]; r.y = acc[i][1]; r.z = acc[i][2]; r.w = acc[i][3];
            *reinterpret_cast<float4*>(out + (size_t)gn * 64 + 4 * tx) = r;
        }
    }
}

// ---------------- fused update (+skip) (+next-layer message p) ----------------
// xout = SKIP(ReLU([A|B] @ Wu + bu)); if HASP: pout = xout @ Wm_next[0:64] + bm_next
template<int K1, bool SKIP, bool HASP>
__global__ __launch_bounds__(256) void fused_update_kernel(
    const float* __restrict__ A, const float* __restrict__ B,
    const float* __restrict__ Wu, const float* __restrict__ bu,
    float* __restrict__ xout,
    const float* __restrict__ Wm_next, const float* __restrict__ bm_next,
    float* __restrict__ pout, int N,
    const float* __restrict__ q0, const float* __restrict__ q1,
    const float* __restrict__ q2, const float* __restrict__ q3,
    const float* __restrict__ q4, const float* __restrict__ q5,
    const float* __restrict__ sw, int swbase, int nprev)
{
    __shared__ float Xs[64 * 68];   // phase1: first 32*68 = As; phase2: xout^T
    __shared__ float Ws[32 * 64];
    int t = threadIdx.x;
    int tx = t & 15, ty = t >> 4;
    int base = blockIdx.x * 64;

    float acc[4][4];
    {
        float4 bv = *reinterpret_cast<const float4*>(bu + 4 * tx);
#pragma unroll
        for (int i = 0; i < 4; ++i) {
            acc[i][0] = bv.x; acc[i][1] = bv.y; acc[i][2] = bv.z; acc[i][3] = bv.w;
        }
    }
    constexpr int C1 = (K1 < 32) ? K1 : 32;
    for (int co = 0; co < K1; co += C1) {
        __syncthreads();
        stage_chunk<C1>(A, K1, co, base, N, Wu, t, Xs, Ws);
        __syncthreads();
        compute_chunk<C1>(Xs, Ws, tx, ty, acc);
    }
    for (int co = 0; co < 64; co += 32) {
        __syncthreads();
        stage_chunk<32>(B, 64, co, base, N, Wu + (size_t)K1 * 64, t, Xs, Ws);
        __syncthreads();
        compute_chunk<32>(Xs, Ws, tx, ty, acc);
    }

    float swself = 1.0f, s0 = 0, s1 = 0, s2 = 0, s3 = 0, s4 = 0, s5 = 0;
    if (SKIP) {
        swself = sw[swbase + nprev];
        if (nprev > 0) s0 = sw[swbase + 0];
        if (nprev > 1) s1 = sw[swbase + 1];
        if (nprev > 2) s2 = sw[swbase + 2];
        if (nprev > 3) s3 = sw[swbase + 3];
        if (nprev > 4) s4 = sw[swbase + 4];
        if (nprev > 5) s5 = sw[swbase + 5];
    }

    float r[4][4];
#pragma unroll
    for (int i = 0; i < 4; ++i) {
        int gn = base + 4 * ty + i;
        bool valid = gn < N;
        float r0 = fmaxf(acc[i][0], 0.0f), r1 = fmaxf(acc[i][1], 0.0f);
        float r2 = fmaxf(acc[i][2], 0.0f), r3 = fmaxf(acc[i][3], 0.0f);
        if (SKIP && valid) {
            size_t off = (size_t)gn * 64 + 4 * tx;
            r0 *= swself; r1 *= swself; r2 *= swself; r3 *= swself;
            if (nprev > 0) { float4 qv = *reinterpret_cast<const float4*>(q0 + off);
                r0 = fmaf(s0, qv.x, r0); r1 = fmaf(s0, qv.y, r1); r2 = fmaf(s0, qv.z, r2); r3 = fmaf(s0, qv.w, r3); }
            if (nprev > 1) { float4 qv = *reinterpret_cast<const float4*>(q1 + off);
                r0 = fmaf(s1, qv.x, r0); r1 = fmaf(s1, qv.y, r1); r2 = fmaf(s1, qv.z, r2); r3 = fmaf(s1, qv.w, r3); }
            if (nprev > 2) { float4 qv = *reinterpret_cast<const float4*>(q2 + off);
                r0 = fmaf(s2, qv.x, r0); r1 = fmaf(s2, qv.y, r1); r2 = fmaf(s2, qv.z, r2); r3 = fmaf(s2, qv.w, r3); }
            if (nprev > 3) { float4 qv = *reinterpret_cast<const float4*>(q3 + off);
                r0 = fmaf(s3, qv.x, r0); r1 = fmaf(s3, qv.y, r1); r2 = fmaf(s3, qv.z, r2); r3 = fmaf(s3, qv.w, r3); }
            if (nprev > 4) { float4 qv = *reinterpret_cast<const float4*>(q4 + off);
                r0 = fmaf(s4, qv.x, r0); r1 = fmaf(s4, qv.y, r1); r2 = fmaf(s4, qv.z, r2); r3 = fmaf(s4, qv.w, r3); }
            if (nprev > 5) { float4 qv = *reinterpret_cast<const float4*>(q5 + off);
                r0 = fmaf(s5, qv.x, r0); r1 = fmaf(s5, qv.y, r1); r2 = fmaf(s5, qv.z, r2); r3 = fmaf(s5, qv.w, r3); }
        }
        r[i][0] = r0; r[i][1] = r1; r[i][2] = r2; r[i][3] = r3;
    }

    __syncthreads();  // all phase-1 LDS reads done before Xs overwrite
#pragma unroll
    for (int i = 0; i < 4; ++i) {
#pragma unroll
        for (int j = 0; j < 4; ++j)
            Xs[(4 * tx + j) * 68 + (4 * ty + i)] = r[i][j];
        int gn = base + 4 * ty + i;
        if (gn < N) {
            float4 rv; rv.x = r[i][0]; rv.y = r[i][1]; rv.z = r[i][2]; rv.w = r[i][3];
            *reinterpret_cast<float4*>(xout + (size_t)gn * 64 + 4 * tx) = rv;
        }
    }

    if (HASP) {
        float acc2[4][4];
        {
            float4 bv = *reinterpret_cast<const float4*>(bm_next + 4 * tx);
#pragma unroll
            for (int i = 0; i < 4; ++i) {
                acc2[i][0] = bv.x; acc2[i][1] = bv.y; acc2[i][2] = bv.z; acc2[i][3] = bv.w;
            }
        }
        for (int co = 0; co < 64; co += 32) {
            __syncthreads();
            {
                const float4* wsrc = reinterpret_cast<const float4*>(Wm_next + (size_t)co * 64);
                float4* wdst = reinterpret_cast<float4*>(Ws);
                for (int idx = t; idx < 32 * 16; idx += 256) wdst[idx] = wsrc[idx];
            }
            __syncthreads();
            compute_chunk<32>(Xs + (size_t)co * 68, Ws, tx, ty, acc2);
        }
#pragma unroll
        for (int i = 0; i < 4; ++i) {
            int gn = base + 4 * ty + i;
            if (gn < N) {
                float4 r2; r2.x = acc2[i][0]; r2.y = acc2[i][1]; r2.z = acc2[i][2]; r2.w = acc2[i][3];
                *reinterpret_cast<float4*>(pout + (size_t)gn * 64 + 4 * tx) = r2;
            }
        }
    }
}

// ---------------- CSR aggregate: 4-edge lane groups, float4/lane ----------------
__global__ __launch_bounds__(256) void csr_agg_kernel(
    const int* __restrict__ rowptr, const int* __restrict__ srcp,
    const float* __restrict__ eap, const float* __restrict__ p,
    const float* __restrict__ Wme, float* __restrict__ agg, int N)
{
    int lane = threadIdx.x & 63;
    int g = lane >> 4;      // edge slot within chunk
    int q = lane & 15;      // feature quad
    int gwave = blockIdx.x * (blockDim.x >> 6) + (threadIdx.x >> 6);
    int nw = gridDim.x * (blockDim.x >> 6);
    float4 w0 = *reinterpret_cast<const float4*>(Wme + 0 * 64 + 4 * q);
    float4 w1 = *reinterpret_cast<const float4*>(Wme + 1 * 64 + 4 * q);
    float4 w2 = *reinterpret_cast<const float4*>(Wme + 2 * 64 + 4 * q);
    float4 w3 = *reinterpret_cast<const float4*>(Wme + 3 * 64 + 4 * q);

    for (int n = gwave; n < N; n += nw) {
        int beg = rowptr[n], end = rowptr[n + 1];
        int deg = end - beg;
        int nc = (deg + 3) >> 2;
        float4 acc = {0, 0, 0, 0};
        // meta for chunk 0 and 1; p for chunk 0
        int sA = 0, sB = 0;
        float4 aA = {0, 0, 0, 0}, aB = {0, 0, 0, 0};
        bool vA = (g < deg);
        bool vB = (4 + g < deg);
        if (vA) { sA = srcp[beg + g];     aA = *reinterpret_cast<const float4*>(eap + (size_t)4 * (beg + g)); }
        if (vB) { sB = srcp[beg + 4 + g]; aB = *reinterpret_cast<const float4*>(eap + (size_t)4 * (beg + 4 + g)); }
        float4 pA = *reinterpret_cast<const float4*>(p + (size_t)sA * 64 + 4 * q);
        for (int c = 0; c < nc; ++c) {
            // meta for chunk c+2
            int sC = 0; float4 aC = {0, 0, 0, 0};
            bool vC = (4 * (c + 2) + g) < deg;
            if (vC) {
                int jc = beg + 4 * (c + 2) + g;
                sC = srcp[jc];
                aC = *reinterpret_cast<const float4*>(eap + (size_t)4 * jc);
            }
            // p for chunk c+1 (sB already resident)
            float4 pB = *reinterpret_cast<const float4*>(p + (size_t)sB * 64 + 4 * q);
            // compute chunk c
            float4 m;
            m.x = fmaf(aA.x, w0.x, fmaf(aA.y, w1.x, fmaf(aA.z, w2.x, fmaf(aA.w, w3.x, pA.x))));
            m.y = fmaf(aA.x, w0.y, fmaf(aA.y, w1.y, fmaf(aA.z, w2.y, fmaf(aA.w, w3.y, pA.y))));
            m.z = fmaf(aA.x, w0.z, fmaf(aA.y, w1.z, fmaf(aA.z, w2.z, fmaf(aA.w, w3.z, pA.z))));
            m.w = fmaf(aA.x, w0.w, fmaf(aA.y, w1.w, fmaf(aA.z, w2.w, fmaf(aA.w, w3.w, pA.w))));
            float f = vA ? 1.0f : 0.0f;
            acc.x = fmaf(f, fmaxf(m.x, 0.0f), acc.x);
            acc.y = fmaf(f, fmaxf(m.y, 0.0f), acc.y);
            acc.z = fmaf(f, fmaxf(m.z, 0.0f), acc.z);
            acc.w = fmaf(f, fmaxf(m.w, 0.0f), acc.w);
            // rotate
            vA = vB; aA = aB; pA = pB;
            vB = vC; aB = aC; sB = sC;
        }
        // reduce across the 4 groups
        acc.x += __shfl_xor(acc.x, 16); acc.y += __shfl_xor(acc.y, 16);
        acc.z += __shfl_xor(acc.z, 16); acc.w += __shfl_xor(acc.w, 16);
        acc.x += __shfl_xor(acc.x, 32); acc.y += __shfl_xor(acc.y, 32);
        acc.z += __shfl_xor(acc.z, 32); acc.w += __shfl_xor(acc.w, 32);
        if (g == 0)
            *reinterpret_cast<float4*>(agg + (size_t)n * 64 + 4 * q) = acc;
    }
}

// ---------------- fallback atomic edge kernel ----------------
__global__ __launch_bounds__(256) void edge_kernel(
    const int* __restrict__ ei, const float* __restrict__ ea,
    const float* __restrict__ p, const float* __restrict__ Wme,
    float* __restrict__ agg, int E)
{
    int lane = threadIdx.x & 63;
    int gwave = blockIdx.x * (blockDim.x >> 6) + (threadIdx.x >> 6);
    int nw = gridDim.x * (blockDim.x >> 6);
    float w0 = Wme[0 * 64 + lane];
    float w1 = Wme[1 * 64 + lane];
    float w2 = Wme[2 * 64 + lane];
    float w3 = Wme[3 * 64 + lane];
    for (int e = gwave; e < E; e += nw) {
        int s = ei[e];
        int d = ei[E + e];
        float4 a = *reinterpret_cast<const float4*>(ea + (size_t)4 * e);
        float v = p[(size_t)s * 64 + lane];
        v = fmaf(a.x, w0, v);
        v = fmaf(a.y, w1, v);
        v = fmaf(a.z, w2, v);
        v = fmaf(a.w, w3, v);
        v = fmaxf(v, 0.0f);
        atomicAdd(agg + (size_t)d * 64 + lane, v);
    }
}

// ---------------- last layer (OUT=4) ----------------
__global__ __launch_bounds__(256) void pl_kernel(
    const float* __restrict__ A, const float* __restrict__ W,
    const float* __restrict__ bias, float* __restrict__ out, int N)
{
    __shared__ float Wl[64 * 4];
    __shared__ float bl[4];
    for (int i = threadIdx.x; i < 256; i += blockDim.x) Wl[i] = W[i];
    if (threadIdx.x < 4) bl[threadIdx.x] = bias[threadIdx.x];
    __syncthreads();
    int t = blockIdx.x * blockDim.x + threadIdx.x;
    int nt = gridDim.x * blockDim.x;
    for (int idx = t; idx < N * 4; idx += nt) {
        int n = idx >> 2, f = idx & 3;
        float acc = bl[f];
        const float* ar = A + (size_t)n * 64;
#pragma unroll
        for (int kk = 0; kk < 16; ++kk) {
            float4 a4 = *reinterpret_cast<const float4*>(ar + 4 * kk);
            acc = fmaf(a4.x, Wl[(4 * kk + 0) * 4 + f], acc);
            acc = fmaf(a4.y, Wl[(4 * kk + 1) * 4 + f], acc);
            acc = fmaf(a4.z, Wl[(4 * kk + 2) * 4 + f], acc);
            acc = fmaf(a4.w, Wl[(4 * kk + 3) * 4 + f], acc);
        }
        out[idx] = acc;
    }
}

__global__ __launch_bounds__(256) void csr_agg4_kernel(
    const int* __restrict__ rowptr, const int* __restrict__ srcp,
    const float* __restrict__ eap, const float* __restrict__ p4,
    const float* __restrict__ Wme, float* __restrict__ agg4, int N)
{
    float w[16];
#pragma unroll
    for (int i = 0; i < 16; ++i) w[i] = Wme[i];
    int t = blockIdx.x * blockDim.x + threadIdx.x;
    int nt = gridDim.x * blockDim.x;
    for (int n = t; n < N; n += nt) {
        int beg = rowptr[n], end = rowptr[n + 1];
        float4 acc = {0, 0, 0, 0};
        for (int j = beg; j < end; ++j) {
            int s = srcp[j];
            float4 a = *reinterpret_cast<const float4*>(eap + (size_t)4 * j);
            float4 pv = *reinterpret_cast<const float4*>(p4 + (size_t)4 * s);
            float vx = pv.x + a.x * w[0] + a.y * w[4] + a.z * w[8]  + a.w * w[12];
            float vy = pv.y + a.x * w[1] + a.y * w[5] + a.z * w[9]  + a.w * w[13];
            float vz = pv.z + a.x * w[2] + a.y * w[6] + a.z * w[10] + a.w * w[14];
            float vw = pv.w + a.x * w[3] + a.y * w[7] + a.z * w[11] + a.w * w[15];
            acc.x += fmaxf(vx, 0.0f);
            acc.y += fmaxf(vy, 0.0f);
            acc.z += fmaxf(vz, 0.0f);
            acc.w += fmaxf(vw, 0.0f);
        }
        *reinterpret_cast<float4*>(agg4 + (size_t)4 * n) = acc;
    }
}

__global__ __launch_bounds__(256) void edge4_kernel(
    const int* __restrict__ ei, const float* __restrict__ ea,
    const float* __restrict__ p4, const float* __restrict__ Wme,
    float* __restrict__ agg4, int E)
{
    int lane = threadIdx.x & 63;
    int f = lane & 3;
    int gwave = blockIdx.x * (blockDim.x >> 6) + (threadIdx.x >> 6);
    int nw = gridDim.x * (blockDim.x >> 6);
    float w0 = Wme[0 * 4 + f];
    float w1 = Wme[1 * 4 + f];
    float w2 = Wme[2 * 4 + f];
    float w3 = Wme[3 * 4 + f];
    for (int e0 = gwave * 16; e0 < E; e0 += nw * 16) {
        int e = e0 + (lane >> 2);
        if (e < E) {
            int s = ei[e];
            int d = ei[E + e];
            float4 a = *reinterpret_cast<const float4*>(ea + (size_t)4 * e);
            float v = p4[(size_t)s * 4 + f];
            v = fmaf(a.x, w0, v);
            v = fmaf(a.y, w1, v);
            v = fmaf(a.z, w2, v);
            v = fmaf(a.w, w3, v);
            v = fmaxf(v, 0.0f);
            atomicAdd(agg4 + (size_t)d * 4 + f, v);
        }
    }
}

__global__ __launch_bounds__(256) void ul_kernel(
    const float* __restrict__ A, const float* __restrict__ agg4,
    const float* __restrict__ W /*[68][4]*/, const float* __restrict__ bias,
    float* __restrict__ out, int N)
{
    __shared__ float Wl[68 * 4];
    __shared__ float bl[4];
    for (int i = threadIdx.x; i < 68 * 4; i += blockDim.x) Wl[i] = W[i];
    if (threadIdx.x < 4) bl[threadIdx.x] = bias[threadIdx.x];
    __syncthreads();
    int t = blockIdx.x * blockDim.x + threadIdx.x;
    int nt = gridDim.x * blockDim.x;
    for (int idx = t; idx < N * 4; idx += nt) {
        int n = idx >> 2, f = idx & 3;
        float acc = bl[f];
        const float* ar = A + (size_t)n * 64;
#pragma unroll
        for (int kk = 0; kk < 16; ++kk) {
            float4 a4 = *reinterpret_cast<const float4*>(ar + 4 * kk);
            acc = fmaf(a4.x, Wl[(4 * kk + 0) * 4 + f], acc);
            acc = fmaf(a4.y, Wl[(4 * kk + 1) * 4 + f], acc);
            acc = fmaf(a4.z, Wl[(4 * kk + 2) * 4 + f], acc);
            acc = fmaf(a4.w, Wl[(4 * kk + 3) * 4 + f], acc);
        }
        float4 g = *reinterpret_cast<const float4*>(agg4 + (size_t)n * 4);
        acc = fmaf(g.x, Wl[(64 + 0) * 4 + f], acc);
        acc = fmaf(g.y, Wl[(64 + 1) * 4 + f], acc);
        acc = fmaf(g.z, Wl[(64 + 2) * 4 + f], acc);
        acc = fmaf(g.w, Wl[(64 + 3) * 4 + f], acc);
        out[idx] = fmaxf(acc, 0.0f);
    }
}

extern "C" void kernel_launch(void* const* d_in, const int* in_sizes, int n_in,
                              void* d_out, int out_size, void* d_ws, size_t ws_size,
                              hipStream_t stream)
{
    const float* x      = (const float*)d_in[0];
    const int*   ei     = (const int*)d_in[1];
    const float* ea     = (const float*)d_in[2];
    const float* Wm1    = (const float*)d_in[3];   // [12][64]
    const float* bm1    = (const float*)d_in[4];
    const float* Wu1    = (const float*)d_in[5];   // [72][64]
    const float* bu1    = (const float*)d_in[6];
    const float* Wm_mid = (const float*)d_in[7];   // [5][68][64]
    const float* bm_mid = (const float*)d_in[8];   // [5][64]
    const float* Wu_mid = (const float*)d_in[9];   // [5][128][64]
    const float* bu_mid = (const float*)d_in[10];  // [5][64]
    const float* WmL    = (const float*)d_in[11];  // [68][4]
    const float* bmL    = (const float*)d_in[12];
    const float* WuL    = (const float*)d_in[13];  // [68][4]
    const float* buL    = (const float*)d_in[14];
    const float* sw     = (const float*)d_in[15];  // [27]

    const int N = in_sizes[0] / 8;
    const int E = in_sizes[2] / 4;

    float* ws = (float*)d_ws;
    size_t nh = (size_t)N * 64;
    float* p    = ws;
    float* agg  = ws + nh;
    float* x1   = ws + 2 * nh;
    float* x2w  = ws + 3 * nh;
    float* x3w  = ws + 4 * nh;
    float* x4w  = ws + 5 * nh;
    float* x5w  = ws + 6 * nh;
    float* x6w  = ws + 7 * nh;
    float* x7w  = p;                  // p free after last mid agg pass
    float* p4   = agg;                // [N*4]
    float* agg4 = agg + (size_t)N * 4;

    // CSR region
    float* eap   = ws + 8 * nh;                 // [E*4]
    int*   srcp  = (int*)(eap + (size_t)E * 4); // [E]
    int*   rowptr= srcp + E;                    // [N+1]
    int*   cursor= rowptr + N + 1;              // [N]
    int*   bsum  = cursor + N;                  // [<=1024]
    size_t need_bytes = (8 * nh + (size_t)E * 4) * 4 + ((size_t)E + 2 * N + 1 + 1024) * 4;
    bool use_csr = ws_size >= need_bytes;

    dim3 blk(256);
    dim3 gEdge(2048), g4(1024);
    dim3 gLin((N + 63) / 64);
    const float* nul = nullptr;

    if (use_csr) {
        int B = (N + 1023) / 1024;
        hipMemsetAsync(cursor, 0, (size_t)N * 4, stream);
        hist_kernel<<<gEdge, blk, 0, stream>>>(ei, cursor, E);
        scan1_kernel<<<dim3(B), blk, 0, stream>>>(cursor, rowptr, bsum, N);
        scan2_kernel<<<dim3(1), blk, 0, stream>>>(bsum, B);
        scan3_kernel<<<dim3(256), blk, 0, stream>>>(rowptr, cursor, bsum, N, E);
        scatter_kernel<<<gEdge, blk, 0, stream>>>(ei, ea, cursor, srcp, eap, E);
    }

    auto edge_pass = [&](const float* pp, const float* Wme, float* aggout) {
        if (use_csr) {
            csr_agg_kernel<<<gEdge, blk, 0, stream>>>(rowptr, srcp, eap, pp, Wme, aggout, N);
        } else {
            hipMemsetAsync(aggout, 0, nh * sizeof(float), stream);
            edge_kernel<<<gEdge, blk, 0, stream>>>(ei, ea, pp, Wme, aggout, E);
        }
    };

    struct MidStep {
        int mi; const float* in; float* out; int swbase; int nprev;
        const float *q0, *q1, *q2, *q3, *q4, *q5;
    };
    MidStep steps[6] = {
        {0, x1,  x2w, 0,  1, x1,  nul, nul, nul, nul, nul},
        {1, x2w, x3w, 2,  2, x1,  x2w, nul, nul, nul, nul},
        {2, x3w, x4w, 5,  3, x1,  x2w, x3w, nul, nul, nul},
        {2, x4w, x5w, 9,  4, x1,  x2w, x3w, x4w, nul, nul},  // reuses mid layer 2 (faithful to bug)
        {3, x5w, x6w, 14, 5, x1,  x2w, x3w, x4w, x5w, nul},
        {4, x6w, x7w, 20, 6, x1,  x2w, x3w, x4w, x5w, x6w},
    };

    // ---- layer 1: message lin, agg, fused update (+p for steps[0]) ----
    lin_kernel<8><<<gLin, blk, 0, stream>>>(x, Wm1, bm1, p, N);
    edge_pass(p, Wm1 + 8 * 64, agg);
    fused_update_kernel<8, false, true><<<gLin, blk, 0, stream>>>(
        x, agg, Wu1, bu1, x1,
        Wm_mid + (size_t)steps[0].mi * 68 * 64, bm_mid + (size_t)steps[0].mi * 64, p, N,
        nul, nul, nul, nul, nul, nul, sw, 0, 0);

    // ---- mid steps ----
    for (int li = 0; li < 6; ++li) {
        const MidStep& st = steps[li];
        const float* Wm = Wm_mid + (size_t)st.mi * 68 * 64;
        const float* Wu = Wu_mid + (size_t)st.mi * 128 * 64;
        const float* bu = bu_mid + (size_t)st.mi * 64;
        edge_pass(p, Wm + 64 * 64, agg);
        if (li < 5) {
            int nmi = steps[li + 1].mi;
            fused_update_kernel<64, true, true><<<gLin, blk, 0, stream>>>(
                st.in, agg, Wu, bu, st.out,
                Wm_mid + (size_t)nmi * 68 * 64, bm_mid + (size_t)nmi * 64, p, N,
                st.q0, st.q1, st.q2, st.q3, st.q4, st.q5, sw, st.swbase, st.nprev);
        } else {
            fused_update_kernel<64, true, false><<<gLin, blk, 0, stream>>>(
                st.in, agg, Wu, bu, st.out,
                nul, nul, nullptr, N,
                st.q0, st.q1, st.q2, st.q3, st.q4, st.q5, sw, st.swbase, st.nprev);
        }
    }

    // ---- last layer (OUT=4) ----
    pl_kernel<<<g4, blk, 0, stream>>>(x7w, WmL, bmL, p4, N);
    if (use_csr) {
        csr_agg4_kernel<<<g4, blk, 0, stream>>>(rowptr, srcp, eap, p4, WmL + 64 * 4, agg4, N);
    } else {
        hipMemsetAsync(agg4, 0, (size_t)N * 4 * sizeof(float), stream);
        edge4_kernel<<<gEdge, blk, 0, stream>>>(ei, ea, p4, WmL + 64 * 4, agg4, E);
    }
    ul_kernel<<<g4, blk, 0, stream>>>(x7w, agg4, WuL, buL, (float*)d_out, N);
}